// Round 1
// baseline (57.792 us; speedup 1.0000x reference)
//
#include <hip/hip_runtime.h>
#include <hip/hip_bf16.h>
#include <stdint.h>

// Problem constants (fixed by the reference)
#define B_SZ 8192
#define D_SZ 256
#define R_SZ 8
#define N_SZ 1024
#define C_SZ (B_SZ / R_SZ)          // 1024
#define CN   (C_SZ * N_SZ)          // 1048576
#define L_SZ (B_SZ + 2 * R_SZ * CN) // 16785408 (logits length)
#define BD   (B_SZ * D_SZ)          // elements per ws array

typedef short bf16x8 __attribute__((ext_vector_type(8)));
typedef float f32x4  __attribute__((ext_vector_type(4)));

static __device__ __forceinline__ unsigned short f2bf(float f) {
  unsigned u = __float_as_uint(f);
  u += 0x7FFFu + ((u >> 16) & 1u);   // RNE
  return (unsigned short)(u >> 16);
}
static __device__ __forceinline__ float bf2f(unsigned short h) {
  return __uint_as_float(((unsigned)h) << 16);
}
static __device__ __forceinline__ float sigmoidf_(float x) {
  return 1.0f / (1.0f + __expf(-x));
}
static __device__ __forceinline__ void gload16(const void* g, void* l) {
  __builtin_amdgcn_global_load_lds(
      (const __attribute__((address_space(1))) void*)g,
      (__attribute__((address_space(3))) void*)l, 16, 0, 0);
}

// ---------------------------------------------------------------------------
// Phase 1: F-reduce emb -> lhs/rhs, split into bf16 hi+lo in ws, pos logits.
// One wave per batch row i. 2048 blocks x 256 threads.
// ---------------------------------------------------------------------------
__global__ __launch_bounds__(256) void prep_kernel(
    const float* __restrict__ emb, const float* __restrict__ trans,
    const int* __restrict__ rels, float* __restrict__ out,
    unsigned short* __restrict__ ws) {
  unsigned short* lhs_hi = ws;
  unsigned short* lhs_lo = ws + (size_t)BD;
  unsigned short* rhs_hi = ws + (size_t)2 * BD;
  unsigned short* rhs_lo = ws + (size_t)3 * BD;

  int wave = threadIdx.x >> 6;
  int lane = threadIdx.x & 63;
  int i = blockIdx.x * 4 + wave;            // 0..B-1

  const float4* emb4 = (const float4*)emb;  // emb row j = 128 float4 (F*D=512 f32)
  size_t bl = (size_t)(2 * i) * 128;
  size_t br = (size_t)(2 * i + 1) * 128;
  float4 a0 = emb4[bl + lane];
  float4 a1 = emb4[bl + 64 + lane];
  float4 b0 = emb4[br + lane];
  float4 b1 = emb4[br + 64 + lane];
  float lh[4] = {a0.x + a1.x, a0.y + a1.y, a0.z + a1.z, a0.w + a1.w};
  float rh[4] = {b0.x + b1.x, b0.y + b1.y, b0.z + b1.z, b0.w + b1.w};

  int rel = rels[i];
  float4 t = ((const float4*)trans)[rel * 64 + lane];
  float tt[4] = {t.x, t.y, t.z, t.w};

  float p = 0.f;
#pragma unroll
  for (int j = 0; j < 4; ++j) p += lh[j] * (rh[j] + tt[j]);
#pragma unroll
  for (int off = 32; off; off >>= 1) p += __shfl_xor(p, off, 64);
  if (lane == 0) {
    out[i] = p;
    out[(size_t)L_SZ + i] = sigmoidf_(p);
  }

  // split-bf16 store: v = hi + lo with |lo_err| <= 2^-18 |v|
  unsigned short h[4], l[4];
#pragma unroll
  for (int j = 0; j < 4; ++j) {
    h[j] = f2bf(lh[j]);
    l[j] = f2bf(lh[j] - bf2f(h[j]));
  }
  *(ushort4*)(lhs_hi + (size_t)i * 256 + lane * 4) = make_ushort4(h[0], h[1], h[2], h[3]);
  *(ushort4*)(lhs_lo + (size_t)i * 256 + lane * 4) = make_ushort4(l[0], l[1], l[2], l[3]);
#pragma unroll
  for (int j = 0; j < 4; ++j) {
    h[j] = f2bf(rh[j]);
    l[j] = f2bf(rh[j] - bf2f(h[j]));
  }
  *(ushort4*)(rhs_hi + (size_t)i * 256 + lane * 4) = make_ushort4(h[0], h[1], h[2], h[3]);
  *(ushort4*)(rhs_lo + (size_t)i * 256 + lane * 4) = make_ushort4(l[0], l[1], l[2], l[3]);
}

// ---------------------------------------------------------------------------
// Phase 2: gather-GEMM negatives. Block = 128x128 output tile of one (r,side).
// side 0: A = rhs[order], B = lhs[neg_lhs_idx];  side 1: A = lhs[order], B = rhs[neg_rhs_idx]
// Split-bf16: acc += Ah*Bh + Al*Bh + Ah*Bl  (3 MFMAs per fragment pair).
// BK=64, 4 K-chunks, 64 KB LDS (Ahi,Alo,Bhi,Blo each [128][64] bf16), 4 waves 2x2.
// XOR source-swizzle (chunk ^ row&7) with linear global_load_lds dest; same XOR
// on ds_read_b128 -> ~conflict-free fragment reads.
// ---------------------------------------------------------------------------
__global__ __launch_bounds__(256, 2) void negs_kernel(
    const unsigned short* __restrict__ ws,
    const int* __restrict__ order,
    const int* __restrict__ negL, const int* __restrict__ negR,
    float* __restrict__ out) {
  __shared__ unsigned short lds[4][128 * 64];  // 64 KB

  const unsigned short* lhs_hi = ws;
  const unsigned short* lhs_lo = ws + (size_t)BD;
  const unsigned short* rhs_hi = ws + (size_t)2 * BD;
  const unsigned short* rhs_lo = ws + (size_t)3 * BD;

  int bid = blockIdx.x;
  int ntile = bid & 7;
  int ctile = (bid >> 3) & 7;
  int side  = (bid >> 6) & 1;
  int r     = bid >> 7;

  int wave = threadIdx.x >> 6;
  int lane = threadIdx.x & 63;
  int wrow = wave >> 1, wcol = wave & 1;

  // wave w stages lds[w]: 0=A_hi 1=A_lo 2=B_hi 3=B_lo
  const unsigned short* srcp;
  const int* idxp;
  int idxbase;
  if (wave < 2) {
    idxp = order;
    idxbase = r * C_SZ + ctile * 128;
    srcp = (wave == 0) ? (side ? lhs_hi : rhs_hi) : (side ? lhs_lo : rhs_lo);
  } else {
    idxp = side ? negR : negL;
    idxbase = r * N_SZ + ntile * 128;
    srcp = (wave == 2) ? (side ? rhs_hi : lhs_hi) : (side ? rhs_lo : lhs_lo);
  }

  // Preload gather offsets: lane stages chunk (lane&7) of row (it*8 + lane>>3).
  // row&7 == lane>>3, so the swizzled chunk offset is lane-constant.
  unsigned goff[16];
#pragma unroll
  for (int it = 0; it < 16; ++it) {
    int grow = idxp[idxbase + it * 8 + (lane >> 3)];
    goff[it] = (unsigned)grow * 512u + ((unsigned)(((lane & 7) ^ (lane >> 3))) << 4);
  }
  unsigned short* myLds = &lds[wave][0];

  f32x4 acc[4][4] = {};

  for (int kc = 0; kc < 4; ++kc) {
    // stage this wave's 16 KB tile (16 x 1KB, linear LDS dest)
#pragma unroll
    for (int it = 0; it < 16; ++it) {
      gload16((const char*)srcp + goff[it] + kc * 128, (char*)myLds + it * 1024);
    }
    __syncthreads();

#pragma unroll
    for (int ks = 0; ks < 2; ++ks) {
      int kchunk = ks * 4 + (lane >> 4);  // 16B chunk index within 128B row
      bf16x8 ah[4], al_[4], bh[4], bl_[4];
#pragma unroll
      for (int mi = 0; mi < 4; ++mi) {
        int row = wrow * 64 + mi * 16 + (lane & 15);
        int off = row * 128 + ((kchunk ^ (lane & 7)) << 4);
        ah[mi]  = *(const bf16x8*)((const char*)&lds[0][0] + off);
        al_[mi] = *(const bf16x8*)((const char*)&lds[1][0] + off);
      }
#pragma unroll
      for (int ni = 0; ni < 4; ++ni) {
        int row = wcol * 64 + ni * 16 + (lane & 15);
        int off = row * 128 + ((kchunk ^ (lane & 7)) << 4);
        bh[ni]  = *(const bf16x8*)((const char*)&lds[2][0] + off);
        bl_[ni] = *(const bf16x8*)((const char*)&lds[3][0] + off);
      }
#pragma unroll
      for (int mi = 0; mi < 4; ++mi)
#pragma unroll
        for (int ni = 0; ni < 4; ++ni) {
          acc[mi][ni] = __builtin_amdgcn_mfma_f32_16x16x32_bf16(ah[mi],  bh[ni],  acc[mi][ni], 0, 0, 0);
          acc[mi][ni] = __builtin_amdgcn_mfma_f32_16x16x32_bf16(al_[mi], bh[ni],  acc[mi][ni], 0, 0, 0);
          acc[mi][ni] = __builtin_amdgcn_mfma_f32_16x16x32_bf16(ah[mi],  bl_[ni], acc[mi][ni], 0, 0, 0);
        }
    }
    __syncthreads();
  }

  // Epilogue: logits + sigmoid. C/D layout: col = lane&15, row = (lane>>4)*4 + j.
  size_t obase = (size_t)B_SZ + ((size_t)(r * 2 + side)) * CN;
#pragma unroll
  for (int mi = 0; mi < 4; ++mi) {
#pragma unroll
    for (int ni = 0; ni < 4; ++ni) {
      int gc = ntile * 128 + wcol * 64 + ni * 16 + (lane & 15);
#pragma unroll
      for (int j = 0; j < 4; ++j) {
        int gr = ctile * 128 + wrow * 64 + mi * 16 + ((lane >> 4) << 2) + j;
        size_t idx = obase + (size_t)gr * N_SZ + gc;
        float v = acc[mi][ni][j];
        out[idx] = v;
        out[(size_t)L_SZ + idx] = sigmoidf_(v);
      }
    }
  }
}

// ---------------------------------------------------------------------------
extern "C" void kernel_launch(void* const* d_in, const int* in_sizes, int n_in,
                              void* d_out, int out_size, void* d_ws, size_t ws_size,
                              hipStream_t stream) {
  const float* emb   = (const float*)d_in[0];
  const float* trans = (const float*)d_in[1];
  const int*   rels  = (const int*)d_in[2];
  const int*   order = (const int*)d_in[3];
  const int*   negL  = (const int*)d_in[4];
  const int*   negR  = (const int*)d_in[5];
  float* out = (float*)d_out;
  unsigned short* ws = (unsigned short*)d_ws;  // 4 * B*D * 2B = 16 MB

  prep_kernel<<<B_SZ / 4, 256, 0, stream>>>(emb, trans, rels, out, ws);
  negs_kernel<<<R_SZ * 2 * 8 * 8, 256, 0, stream>>>(ws, order, negL, negR, out);
}